// Round 4
// baseline (54.966 us; speedup 1.0000x reference)
//
#include <hip/hip_runtime.h>

// out[j] = sum_i alpha[i] * T[lab_obs[i], lab_x[j]] * matern52(xobs[i], x[j]; ls)
// N = M = 8192, D = 8, ND = 4; domain edges are multiples of 2048.
//
// pack_rows: xobs row -> {bf16-hi x8 | bf16-lo x8} (scaled by -2/ls^2, 32B) in pk,
//            {na, alpha} (8B) in pkb; also zeroes out[].
// matern_main: barrier-free, LDS-free. Each wave owns 32 columns (2 MFMA B-frags,
// held in registers) and streams 256 rows of packed A-fragments + seeds straight
// from global (L1/L2 resident) with 1-deep register prefetch.
// sq_ij = na_i + nb_j + A.B via mfma_f32_16x16x32_bf16 (split-bf16 K-packing:
// A=[hi|lo|hi|x], B=[bhi|bhi|blo|0]). Matern tail on VALU. The transfer factor
// w is uniform per block (row-slice and col-tile each sit in one domain) and is
// applied once at the final atomicAdd.

typedef __attribute__((ext_vector_type(8))) short short8v;
typedef __attribute__((ext_vector_type(4))) float f32x4;
typedef __attribute__((ext_vector_type(4))) unsigned int u32x4;

#define BLOCK 256
#define DPT 8
#define COLS_PER_BLOCK 128
#define ROWS_PER_BLOCK 256
#define PKSTRIDE 8          // floats per packed row (32B: hi x4 | lo x4 words)

__device__ __forceinline__ void split_pair(float a0, float a1,
                                           unsigned& hi, unsigned& lo) {
    unsigned u0 = __builtin_bit_cast(unsigned, a0);
    unsigned u1 = __builtin_bit_cast(unsigned, a1);
    unsigned h0 = u0 & 0xffff0000u, h1 = u1 & 0xffff0000u;
    float r0 = a0 - __builtin_bit_cast(float, h0);
    float r1 = a1 - __builtin_bit_cast(float, h1);
    unsigned l0 = __builtin_bit_cast(unsigned, r0);
    unsigned l1 = __builtin_bit_cast(unsigned, r1);
    hi = (h0 >> 16) | h1;
    lo = (l0 >> 16) | (l1 & 0xffff0000u);
}

__global__ __launch_bounds__(256) void pack_rows(
    const float* __restrict__ xobs, const float* __restrict__ alpha,
    const float* __restrict__ ls,
    float* __restrict__ pk, float* __restrict__ pkb,
    float* __restrict__ out, int N, int NP, int M)
{
    const int i = blockIdx.x * 256 + threadIdx.x;
    // zero the output accumulator (replaces a memset dispatch)
    for (int k = i; k < M; k += gridDim.x * 256) out[k] = 0.0f;
    if (i >= NP) return;
    if (i < N) {
        const float rls  = 1.0f / ls[0];
        const float rls2 = rls * rls;
        const float m2   = -2.0f * rls2;
        float4 p0 = *(const float4*)(xobs + (size_t)i * DPT);
        float4 p1 = *(const float4*)(xobs + (size_t)i * DPT + 4);
        float vv[8] = {p0.x, p0.y, p0.z, p0.w, p1.x, p1.y, p1.z, p1.w};
        float na = 0.0f;
        unsigned hi[4], lo[4];
        #pragma unroll
        for (int k = 0; k < 4; ++k) {
            float a0 = vv[2*k], a1 = vv[2*k+1];
            na += a0*a0 + a1*a1;
            split_pair(a0*m2, a1*m2, hi[k], lo[k]);
        }
        na *= rls2;
        *(uint4*)(pk + (size_t)i * PKSTRIDE)     = make_uint4(hi[0], hi[1], hi[2], hi[3]);
        *(uint4*)(pk + (size_t)i * PKSTRIDE + 4) = make_uint4(lo[0], lo[1], lo[2], lo[3]);
        *(float2*)(pkb + (size_t)i * 2) = make_float2(na, alpha[i]);
    } else {
        *(uint4*)(pk + (size_t)i * PKSTRIDE)     = make_uint4(0u, 0u, 0u, 0u);
        *(uint4*)(pk + (size_t)i * PKSTRIDE + 4) = make_uint4(0u, 0u, 0u, 0u);
        *(float2*)(pkb + (size_t)i * 2) = make_float2(0.0f, 0.0f);
    }
}

__global__ __launch_bounds__(256, 6) void matern_main(
    const float* __restrict__ x, const float* __restrict__ pk,
    const float* __restrict__ pkb, const float* __restrict__ tfl,
    const float* __restrict__ ls, const int* __restrict__ dro,
    const int* __restrict__ drx,
    float* __restrict__ out, int M, int ND)
{
    const int tid  = threadIdx.x;
    const int wave = tid >> 6;
    const int lane = tid & 63;
    const int g    = lane >> 4;
    const int r15  = lane & 15;

    const int colBase = blockIdx.x * COLS_PER_BLOCK;
    const int rowBase = blockIdx.y * ROWS_PER_BLOCK;

    // block-uniform transfer factor (tiles sit inside single domains)
    int labj = ND, labi = ND;
    for (int d = 0; d < ND; ++d) {
        if (colBase >= drx[2*d] && colBase < drx[2*d+1]) labj = d;
        if (rowBase >= dro[2*d] && rowBase < dro[2*d+1]) labi = d;
    }
    float w = 1.0f;
    if (labi != labj && labi < ND && labj < ND) {
        int a_ = min(labi, labj), b_ = max(labi, labj);
        int n  = a_ * (2*ND - a_ - 1) / 2 + (b_ - a_ - 1);
        w = 1.0f / (1.0f + __expf(-tfl[n]));
    }

    // ---- column fragments: 2 groups of 16 columns per wave, in registers ----
    const float rls  = 1.0f / ls[0];
    const float rls2 = rls * rls;
    const int j0 = colBase + wave * 32 + r15;
    const int j1 = j0 + 16;
    float nb[2]; short8v bfrag[2];
    #pragma unroll
    for (int c = 0; c < 2; ++c) {
        const int j = (c == 0) ? j0 : j1;
        float vv[8];
        if (j < M) {
            float4 p0 = *(const float4*)(x + (size_t)j * DPT);
            float4 p1 = *(const float4*)(x + (size_t)j * DPT + 4);
            vv[0]=p0.x; vv[1]=p0.y; vv[2]=p0.z; vv[3]=p0.w;
            vv[4]=p1.x; vv[5]=p1.y; vv[6]=p1.z; vv[7]=p1.w;
        } else {
            #pragma unroll
            for (int k = 0; k < 8; ++k) vv[k] = 0.0f;
        }
        float s2 = 0.0f;
        unsigned bh[4], bl[4];
        #pragma unroll
        for (int k = 0; k < 4; ++k) {
            s2 += vv[2*k]*vv[2*k] + vv[2*k+1]*vv[2*k+1];
            split_pair(vv[2*k], vv[2*k+1], bh[k], bl[k]);
        }
        nb[c] = s2 * rls2;
        u32x4 bw;
        #pragma unroll
        for (int k = 0; k < 4; ++k)
            bw[k] = (g == 3) ? 0u : ((g == 2) ? bl[k] : bh[k]);
        bfrag[c] = __builtin_bit_cast(short8v, bw);
    }

    // ---- row stream: A-fragments + seeds from global, 1-deep prefetch ----
    const float* pa = pk  + (size_t)(rowBase + r15) * PKSTRIDE + ((g == 1) ? 4 : 0);
    const float* ps = pkb + (size_t)(rowBase + g * 4) * 2;

    const float SQRT5 = 2.23606797749979f;
    const float C53   = 1.6666666666666667f;   // 5/3
    const float EXPC  = -3.2259645291206594f;  // -sqrt5 * log2(e)

    uint4  aC  = *(const uint4*)pa;
    float4 sC0 = *(const float4*)ps;        // {na[g4], al[g4], na[g4+1], al[g4+1]}
    float4 sC1 = *(const float4*)(ps + 4);  // rows g4+2, g4+3
    float acc0 = 0.0f, acc1 = 0.0f;

    const int NIT = ROWS_PER_BLOCK / 16;
    #pragma unroll 4
    for (int it = 0; it < NIT; ++it) {
        uint4 aN; float4 sN0, sN1;
        if (it + 1 < NIT) {
            pa += 16 * PKSTRIDE;
            ps += 32;
            aN  = *(const uint4*)pa;
            sN0 = *(const float4*)ps;
            sN1 = *(const float4*)(ps + 4);
        }

        short8v afrag = __builtin_bit_cast(short8v, aC);
        f32x4 c0, c1; float awr[4];
        c0[0] = sC0.x + nb[0]; c0[1] = sC0.z + nb[0];
        c0[2] = sC1.x + nb[0]; c0[3] = sC1.z + nb[0];
        c1[0] = sC0.x + nb[1]; c1[1] = sC0.z + nb[1];
        c1[2] = sC1.x + nb[1]; c1[3] = sC1.z + nb[1];
        awr[0] = sC0.y; awr[1] = sC0.w; awr[2] = sC1.y; awr[3] = sC1.w;

        f32x4 d0 = __builtin_amdgcn_mfma_f32_16x16x32_bf16(afrag, bfrag[0], c0, 0, 0, 0);
        f32x4 d1 = __builtin_amdgcn_mfma_f32_16x16x32_bf16(afrag, bfrag[1], c1, 0, 0, 0);

        #pragma unroll
        for (int q = 0; q < 4; ++q) {
            float sq0 = fmaxf(d0[q], 1e-12f);
            float dd0 = __builtin_amdgcn_sqrtf(sq0);
            float e0  = __builtin_amdgcn_exp2f(EXPC * dd0);
            float p0  = fmaf(SQRT5, dd0, fmaf(C53, sq0, 1.0f));
            acc0      = fmaf(p0 * e0, awr[q], acc0);
            float sq1 = fmaxf(d1[q], 1e-12f);
            float dd1 = __builtin_amdgcn_sqrtf(sq1);
            float e1  = __builtin_amdgcn_exp2f(EXPC * dd1);
            float p1  = fmaf(SQRT5, dd1, fmaf(C53, sq1, 1.0f));
            acc1      = fmaf(p1 * e1, awr[q], acc1);
        }

        aC = aN; sC0 = sN0; sC1 = sN1;
    }

    // reduce the 4 k/D-row groups (lanes r15, +16, +32, +48), apply w, accumulate
    acc0 += __shfl_xor(acc0, 16);
    acc0 += __shfl_xor(acc0, 32);
    acc1 += __shfl_xor(acc1, 16);
    acc1 += __shfl_xor(acc1, 32);
    if (g == 0) {
        if (j0 < M) atomicAdd(&out[j0], w * acc0);
        if (j1 < M) atomicAdd(&out[j1], w * acc1);
    }
}

extern "C" void kernel_launch(void* const* d_in, const int* in_sizes, int n_in,
                              void* d_out, int out_size, void* d_ws, size_t ws_size,
                              hipStream_t stream) {
    const float* x     = (const float*)d_in[0];
    const float* xobs  = (const float*)d_in[1];
    const float* alpha = (const float*)d_in[2];
    const float* tfl   = (const float*)d_in[3];
    const float* ls    = (const float*)d_in[4];
    const int*   dro   = (const int*)d_in[5];
    const int*   drx   = (const int*)d_in[6];
    float* out = (float*)d_out;

    const int M  = in_sizes[0] / DPT;
    const int N  = in_sizes[1] / DPT;
    const int ND = in_sizes[5] / 2;
    const int NP = (N + ROWS_PER_BLOCK - 1) & ~(ROWS_PER_BLOCK - 1);

    float* pk  = (float*)d_ws;                     // NP * 32 B
    float* pkb = (float*)d_ws + (size_t)NP * PKSTRIDE;  // NP * 8 B

    pack_rows<<<dim3((NP + 255) / 256), dim3(256), 0, stream>>>(
        xobs, alpha, ls, pk, pkb, out, N, NP, M);

    dim3 grid((M + COLS_PER_BLOCK - 1) / COLS_PER_BLOCK, NP / ROWS_PER_BLOCK);
    matern_main<<<grid, dim3(BLOCK), 0, stream>>>(
        x, pk, pkb, tfl, ls, dro, drx, out, M, ND);
}

// Round 5
// 45.116 us; speedup vs baseline: 1.2183x; 1.2183x over previous
//
#include <hip/hip_runtime.h>

// out[j] = sum_i alpha[i] * T[lab_obs[i], lab_x[j]] * matern52(xobs[i], x[j]; ls)
// N = M = 8192, D = 8, ND = 4; domain edges are multiples of 2048.
//
// pack_rows:  xobs row i -> 32B MFMA A-fragment {bf16-hi x8 | bf16-lo x8},
//             scaled by -2/ls^2, stored XOR-swizzled (byte ^= (i&7)<<4) so a
//             LINEAR global_load_lds placement gives conflict-free ds_read_b128.
//             Seeds stored SoA per 256-row block: [na[256] | alpha[256]] (2KB).
// matern_main: per block = 128 cols x 256 rows. Stage 10KB via
//             global_load_lds width=16 (one barrier), then 16 MFMA+tail iters.
//             sq_ij = na_i + nb_j + A.B via mfma_f32_16x16x32_bf16, split-bf16
//             K-packing A=[hi|lo|hi|x], B=[bhi|bhi|blo|0]. Matern tail on VALU.
//             Block-uniform transfer factor folded into the partial store.
//             NO atomics: partials to d_ws, reduced by reduce_cols.

typedef __attribute__((ext_vector_type(8))) short short8v;
typedef __attribute__((ext_vector_type(4))) float f32x4;
typedef __attribute__((ext_vector_type(4))) unsigned int u32x4;
typedef unsigned int u32;

#define BLOCK 256
#define DPT 8
#define COLS_PER_BLOCK 128
#define ROWS_PER_BLOCK 256

__device__ __forceinline__ void split_pair(float a0, float a1,
                                           unsigned& hi, unsigned& lo) {
    unsigned u0 = __builtin_bit_cast(unsigned, a0);
    unsigned u1 = __builtin_bit_cast(unsigned, a1);
    unsigned h0 = u0 & 0xffff0000u, h1 = u1 & 0xffff0000u;
    float r0 = a0 - __builtin_bit_cast(float, h0);
    float r1 = a1 - __builtin_bit_cast(float, h1);
    unsigned l0 = __builtin_bit_cast(unsigned, r0);
    unsigned l1 = __builtin_bit_cast(unsigned, r1);
    hi = (h0 >> 16) | h1;
    lo = (l0 >> 16) | (l1 & 0xffff0000u);
}

__device__ __forceinline__ void gll16(const void* g, void* l) {
    __builtin_amdgcn_global_load_lds(
        (const __attribute__((address_space(1))) u32*)g,
        (__attribute__((address_space(3))) u32*)l, 16, 0, 0);
}

__global__ __launch_bounds__(256) void pack_rows(
    const float* __restrict__ xobs, const float* __restrict__ alpha,
    const float* __restrict__ ls,
    char* __restrict__ pkA, float* __restrict__ pkS,
    int N, int NP)
{
    const int i = blockIdx.x * 256 + threadIdx.x;
    if (i >= NP) return;
    unsigned hi[4] = {0,0,0,0}, lo[4] = {0,0,0,0};
    float na = 0.0f, al = 0.0f;
    if (i < N) {
        const float rls  = 1.0f / ls[0];
        const float rls2 = rls * rls;
        const float m2   = -2.0f * rls2;
        float4 p0 = *(const float4*)(xobs + (size_t)i * DPT);
        float4 p1 = *(const float4*)(xobs + (size_t)i * DPT + 4);
        float vv[8] = {p0.x, p0.y, p0.z, p0.w, p1.x, p1.y, p1.z, p1.w};
        #pragma unroll
        for (int k = 0; k < 4; ++k) {
            float a0 = vv[2*k], a1 = vv[2*k+1];
            na += a0*a0 + a1*a1;
            split_pair(a0*m2, a1*m2, hi[k], lo[k]);
        }
        na *= rls2;
        al  = alpha[i];
    }
    // XOR-swizzled fragment placement (bijective within each 8-row stripe)
    const size_t bh = ((size_t)i * 32 +  0) ^ (size_t)((i & 7) << 4);
    const size_t bl = ((size_t)i * 32 + 16) ^ (size_t)((i & 7) << 4);
    *(uint4*)(pkA + bh) = make_uint4(hi[0], hi[1], hi[2], hi[3]);
    *(uint4*)(pkA + bl) = make_uint4(lo[0], lo[1], lo[2], lo[3]);
    const int blk = i >> 8, r = i & 255;
    pkS[(size_t)blk * 512 + r]       = na;
    pkS[(size_t)blk * 512 + 256 + r] = al;
}

__global__ __launch_bounds__(256, 6) void matern_main(
    const float* __restrict__ x, const char* __restrict__ pkA,
    const float* __restrict__ pkS, const float* __restrict__ tfl,
    const float* __restrict__ ls, const int* __restrict__ dro,
    const int* __restrict__ drx,
    float* __restrict__ part, int M, int ND)
{
    __shared__ __align__(16) char lds[10240];  // [0,8K)=frags, [8K,9K)=na, [9K,10K)=al

    const int tid  = threadIdx.x;
    const int wave = tid >> 6;
    const int lane = tid & 63;
    const int g    = lane >> 4;
    const int r15  = lane & 15;

    const int colBase = blockIdx.x * COLS_PER_BLOCK;
    const int rowBase = blockIdx.y * ROWS_PER_BLOCK;

    // ---- stage: 8 fragment chunks + 2 seed chunks of 1KB, linear LDS ----
    {
        const char* gA = pkA + (size_t)blockIdx.y * (ROWS_PER_BLOCK * 32);
        const char* gS = (const char*)(pkS + (size_t)blockIdx.y * 512);
        #pragma unroll
        for (int c0 = 0; c0 < 12; c0 += 4) {
            int c = c0 + wave;
            if (c < 10) {
                const char* src = (c < 8) ? (gA + c * 1024 + lane * 16)
                                          : (gS + (c - 8) * 1024 + lane * 16);
                gll16(src, lds + c * 1024);
            }
        }
    }

    // ---- block-uniform transfer factor ----
    int labj = ND, labi = ND;
    for (int d = 0; d < ND; ++d) {
        if (colBase >= drx[2*d] && colBase < drx[2*d+1]) labj = d;
        if (rowBase >= dro[2*d] && rowBase < dro[2*d+1]) labi = d;
    }
    float w = 1.0f;
    if (labi != labj && labi < ND && labj < ND) {
        int a_ = min(labi, labj), b_ = max(labi, labj);
        int n  = a_ * (2*ND - a_ - 1) / 2 + (b_ - a_ - 1);
        w = 1.0f / (1.0f + __expf(-tfl[n]));
    }

    // ---- column fragments: 2 groups of 16 columns per wave, in registers ----
    const float rls  = 1.0f / ls[0];
    const float rls2 = rls * rls;
    const int j0 = colBase + wave * 32 + r15;
    const int j1 = j0 + 16;
    float nb[2]; short8v bfrag[2];
    #pragma unroll
    for (int c = 0; c < 2; ++c) {
        const int j = (c == 0) ? j0 : j1;
        float vv[8];
        if (j < M) {
            float4 p0 = *(const float4*)(x + (size_t)j * DPT);
            float4 p1 = *(const float4*)(x + (size_t)j * DPT + 4);
            vv[0]=p0.x; vv[1]=p0.y; vv[2]=p0.z; vv[3]=p0.w;
            vv[4]=p1.x; vv[5]=p1.y; vv[6]=p1.z; vv[7]=p1.w;
        } else {
            #pragma unroll
            for (int k = 0; k < 8; ++k) vv[k] = 0.0f;
        }
        float s2 = 0.0f;
        unsigned bh[4], bl[4];
        #pragma unroll
        for (int k = 0; k < 4; ++k) {
            s2 += vv[2*k]*vv[2*k] + vv[2*k+1]*vv[2*k+1];
            split_pair(vv[2*k], vv[2*k+1], bh[k], bl[k]);
        }
        nb[c] = s2 * rls2;
        u32x4 bw;
        #pragma unroll
        for (int k = 0; k < 4; ++k)
            bw[k] = (g == 3) ? 0u : ((g == 2) ? bl[k] : bh[k]);
        bfrag[c] = __builtin_bit_cast(short8v, bw);
    }

    asm volatile("s_waitcnt vmcnt(0)" ::: "memory");
    __syncthreads();

    // ---- compute: 16 iterations of 16 rows x 32 cols ----
    const float SQRT5 = 2.23606797749979f;
    const float C53   = 1.6666666666666667f;   // 5/3
    const float EXPC  = -3.2259645291206594f;  // -sqrt5 * log2(e)

    // lane's swizzled fragment base: row r15, half h=(g==1)
    const int h     = (g == 1) ? 1 : 0;
    const int abase = ((r15 * 32 + h * 16) ^ ((r15 & 7) << 4));

    float acc0 = 0.0f, acc1 = 0.0f;
    #pragma unroll
    for (int it = 0; it < ROWS_PER_BLOCK / 16; ++it) {
        short8v afrag = *(const short8v*)(lds + abase + it * 512);
        f32x4 cna = *(const f32x4*)(lds + 8192 + it * 64 + g * 16);
        f32x4 cal = *(const f32x4*)(lds + 9216 + it * 64 + g * 16);
        f32x4 c0, c1;
        #pragma unroll
        for (int q = 0; q < 4; ++q) { c0[q] = cna[q] + nb[0]; c1[q] = cna[q] + nb[1]; }

        f32x4 d0 = __builtin_amdgcn_mfma_f32_16x16x32_bf16(afrag, bfrag[0], c0, 0, 0, 0);
        f32x4 d1 = __builtin_amdgcn_mfma_f32_16x16x32_bf16(afrag, bfrag[1], c1, 0, 0, 0);

        #pragma unroll
        for (int q = 0; q < 4; ++q) {
            float sq0 = fmaxf(d0[q], 1e-12f);
            float dd0 = __builtin_amdgcn_sqrtf(sq0);
            float e0  = __builtin_amdgcn_exp2f(EXPC * dd0);
            float p0  = fmaf(SQRT5, dd0, fmaf(C53, sq0, 1.0f));
            acc0      = fmaf(p0 * e0, cal[q], acc0);
            float sq1 = fmaxf(d1[q], 1e-12f);
            float dd1 = __builtin_amdgcn_sqrtf(sq1);
            float e1  = __builtin_amdgcn_exp2f(EXPC * dd1);
            float p1  = fmaf(SQRT5, dd1, fmaf(C53, sq1, 1.0f));
            acc1      = fmaf(p1 * e1, cal[q], acc1);
        }
    }

    // reduce over the 4 row-groups; lanes 0-15 of each wave hold column sums
    acc0 += __shfl_xor(acc0, 16);
    acc0 += __shfl_xor(acc0, 32);
    acc1 += __shfl_xor(acc1, 16);
    acc1 += __shfl_xor(acc1, 32);
    if (g == 0) {
        float* dst = part + (size_t)blockIdx.y * M;
        if (j0 < M) dst[j0] = w * acc0;
        if (j1 < M) dst[j1] = w * acc1;
    }
}

__global__ __launch_bounds__(256) void reduce_cols(
    const float* __restrict__ part, float* __restrict__ out,
    int M, int nparts)
{
    const int j4 = (blockIdx.x * 256 + threadIdx.x) * 4;
    if (j4 >= M) return;
    float a0 = 0.0f, a1 = 0.0f, a2 = 0.0f, a3 = 0.0f;
    for (int k = 0; k < nparts; ++k) {
        float4 v = *(const float4*)(part + (size_t)k * M + j4);
        a0 += v.x; a1 += v.y; a2 += v.z; a3 += v.w;
    }
    *(float4*)(out + j4) = make_float4(a0, a1, a2, a3);
}

extern "C" void kernel_launch(void* const* d_in, const int* in_sizes, int n_in,
                              void* d_out, int out_size, void* d_ws, size_t ws_size,
                              hipStream_t stream) {
    const float* x     = (const float*)d_in[0];
    const float* xobs  = (const float*)d_in[1];
    const float* alpha = (const float*)d_in[2];
    const float* tfl   = (const float*)d_in[3];
    const float* ls    = (const float*)d_in[4];
    const int*   dro   = (const int*)d_in[5];
    const int*   drx   = (const int*)d_in[6];
    float* out = (float*)d_out;

    const int M  = in_sizes[0] / DPT;
    const int N  = in_sizes[1] / DPT;
    const int ND = in_sizes[5] / 2;
    const int NP = (N + ROWS_PER_BLOCK - 1) & ~(ROWS_PER_BLOCK - 1);
    const int nparts = NP / ROWS_PER_BLOCK;

    char*  pkA  = (char*)d_ws;                         // NP * 32 B
    float* pkS  = (float*)(pkA + (size_t)NP * 32);     // NP * 8 B (SoA blocks)
    float* part = pkS + (size_t)NP * 2;                // nparts * M * 4 B

    pack_rows<<<dim3(NP / 256), dim3(256), 0, stream>>>(
        xobs, alpha, ls, pkA, pkS, N, NP);

    dim3 grid((M + COLS_PER_BLOCK - 1) / COLS_PER_BLOCK, nparts);
    matern_main<<<grid, dim3(BLOCK), 0, stream>>>(
        x, pkA, pkS, tfl, ls, dro, drx, part, M, ND);

    reduce_cols<<<dim3((M + 1023) / 1024), dim3(256), 0, stream>>>(
        part, out, M, nparts);
}

// Round 6
// 42.923 us; speedup vs baseline: 1.2806x; 1.0511x over previous
//
#include <hip/hip_runtime.h>

// out[j] = sum_i alpha[i] * T[lab_obs[i], lab_x[j]] * matern52(xobs[i], x[j]; ls)
// N = M = 8192, D = 8, ND = 4; domain edges are multiples of 2048.
//
// Single fused main kernel: each block owns 128 cols x 256 rows.
//  - prologue: thread t packs xobs row (rowBase+t) into LDS as a 32B split-bf16
//    MFMA A-fragment {hi x8 | lo x8} scaled by -2/ls^2, XOR-swizzled
//    (byte ^= (row&7)<<4) for conflict-free ds_read_b128; na/alpha as SoA.
//    One barrier. (Packing is redundant across the 64 col-blocks but costs
//    ~0.2us chip-wide; xobs is L2-resident.)
//  - main loop: 16 iters, explicitly software-pipelined: issue ds_reads+MFMAs
//    for iter k+1, then run the Matern tail for iter k's results (8 independent
//    sqrt/exp2 chains) while the MFMAs execute.
//  - sq_ij = na_i + nb_j + A.B via mfma_f32_16x16x32_bf16, split-bf16 K-packing
//    A=[hi|lo|hi|x], B=[bhi|bhi|blo|0]. Block-uniform transfer factor folded
//    into the partial store. No atomics: partials to d_ws, reduced by reduce_cols.

typedef __attribute__((ext_vector_type(8))) short short8v;
typedef __attribute__((ext_vector_type(4))) float f32x4;
typedef __attribute__((ext_vector_type(4))) unsigned int u32x4;

#define BLOCK 256
#define DPT 8
#define COLS_PER_BLOCK 128
#define ROWS_PER_BLOCK 256
#define NIT (ROWS_PER_BLOCK / 16)

__device__ __forceinline__ void split_pair(float a0, float a1,
                                           unsigned& hi, unsigned& lo) {
    unsigned u0 = __builtin_bit_cast(unsigned, a0);
    unsigned u1 = __builtin_bit_cast(unsigned, a1);
    unsigned h0 = u0 & 0xffff0000u, h1 = u1 & 0xffff0000u;
    float r0 = a0 - __builtin_bit_cast(float, h0);
    float r1 = a1 - __builtin_bit_cast(float, h1);
    unsigned l0 = __builtin_bit_cast(unsigned, r0);
    unsigned l1 = __builtin_bit_cast(unsigned, r1);
    hi = (h0 >> 16) | h1;
    lo = (l0 >> 16) | (l1 & 0xffff0000u);
}

__global__ __launch_bounds__(256) void matern_main(
    const float* __restrict__ x, const float* __restrict__ xobs,
    const float* __restrict__ alpha, const float* __restrict__ tfl,
    const float* __restrict__ ls, const int* __restrict__ dro,
    const int* __restrict__ drx,
    float* __restrict__ part, int M, int N, int ND)
{
    __shared__ __align__(16) char lds[10240]; // [0,8K)=frags, [8K,9K)=na, [9K,10K)=al

    const int tid  = threadIdx.x;
    const int wave = tid >> 6;
    const int lane = tid & 63;
    const int g    = lane >> 4;
    const int r15  = lane & 15;

    const int colBase = blockIdx.x * COLS_PER_BLOCK;
    const int rowBase = blockIdx.y * ROWS_PER_BLOCK;

    const float rls  = 1.0f / ls[0];
    const float rls2 = rls * rls;
    const float m2   = -2.0f * rls2;

    // ---- in-block pack: thread t -> row rowBase+t into swizzled LDS ----
    {
        const int i = rowBase + tid;
        unsigned hi[4] = {0,0,0,0}, lo[4] = {0,0,0,0};
        float na = 0.0f, al = 0.0f;
        if (i < N) {
            float4 p0 = *(const float4*)(xobs + (size_t)i * DPT);
            float4 p1 = *(const float4*)(xobs + (size_t)i * DPT + 4);
            float vv[8] = {p0.x, p0.y, p0.z, p0.w, p1.x, p1.y, p1.z, p1.w};
            #pragma unroll
            for (int k = 0; k < 4; ++k) {
                float a0 = vv[2*k], a1 = vv[2*k+1];
                na += a0*a0 + a1*a1;
                split_pair(a0*m2, a1*m2, hi[k], lo[k]);
            }
            na *= rls2;
            al  = alpha[i];
        }
        const int swz = (tid & 7) << 4;
        *(u32x4*)(lds + ((tid * 32 +  0) ^ swz)) = u32x4{hi[0], hi[1], hi[2], hi[3]};
        *(u32x4*)(lds + ((tid * 32 + 16) ^ swz)) = u32x4{lo[0], lo[1], lo[2], lo[3]};
        *(float*)(lds + 8192 + tid * 4) = na;
        *(float*)(lds + 9216 + tid * 4) = al;
    }

    // ---- block-uniform transfer factor ----
    int labj = ND, labi = ND;
    for (int d = 0; d < ND; ++d) {
        if (colBase >= drx[2*d] && colBase < drx[2*d+1]) labj = d;
        if (rowBase >= dro[2*d] && rowBase < dro[2*d+1]) labi = d;
    }
    float w = 1.0f;
    if (labi != labj && labi < ND && labj < ND) {
        int a_ = min(labi, labj), b_ = max(labi, labj);
        int n  = a_ * (2*ND - a_ - 1) / 2 + (b_ - a_ - 1);
        w = 1.0f / (1.0f + __expf(-tfl[n]));
    }

    // ---- column fragments: 2 groups of 16 columns per wave, in registers ----
    const int j0 = colBase + wave * 32 + r15;
    const int j1 = j0 + 16;
    float nb[2]; short8v bfrag[2];
    #pragma unroll
    for (int c = 0; c < 2; ++c) {
        const int j = (c == 0) ? j0 : j1;
        float vv[8];
        if (j < M) {
            float4 p0 = *(const float4*)(x + (size_t)j * DPT);
            float4 p1 = *(const float4*)(x + (size_t)j * DPT + 4);
            vv[0]=p0.x; vv[1]=p0.y; vv[2]=p0.z; vv[3]=p0.w;
            vv[4]=p1.x; vv[5]=p1.y; vv[6]=p1.z; vv[7]=p1.w;
        } else {
            #pragma unroll
            for (int k = 0; k < 8; ++k) vv[k] = 0.0f;
        }
        float s2 = 0.0f;
        unsigned bh[4], bl[4];
        #pragma unroll
        for (int k = 0; k < 4; ++k) {
            s2 += vv[2*k]*vv[2*k] + vv[2*k+1]*vv[2*k+1];
            split_pair(vv[2*k], vv[2*k+1], bh[k], bl[k]);
        }
        nb[c] = s2 * rls2;
        u32x4 bw;
        #pragma unroll
        for (int k = 0; k < 4; ++k)
            bw[k] = (g == 3) ? 0u : ((g == 2) ? bl[k] : bh[k]);
        bfrag[c] = __builtin_bit_cast(short8v, bw);
    }

    __syncthreads();

    // ---- pipelined compute: 16 iterations of 16 rows x 32 cols ----
    const float SQRT5 = 2.23606797749979f;
    const float C53   = 1.6666666666666667f;   // 5/3
    const float EXPC  = -3.2259645291206594f;  // -sqrt5 * log2(e)

    const int abase = (r15 * 32 + ((g == 1) ? 16 : 0)) ^ ((r15 & 7) << 4);

    float acc0 = 0.0f, acc1 = 0.0f;

    // prologue: iter 0 loads + MFMAs
    f32x4 e0p, e1p, calp;
    {
        short8v aF = *(const short8v*)(lds + abase);
        f32x4 cna  = *(const f32x4*)(lds + 8192 + g * 16);
        calp       = *(const f32x4*)(lds + 9216 + g * 16);
        f32x4 c0, c1;
        #pragma unroll
        for (int q = 0; q < 4; ++q) { c0[q] = cna[q] + nb[0]; c1[q] = cna[q] + nb[1]; }
        e0p = __builtin_amdgcn_mfma_f32_16x16x32_bf16(aF, bfrag[0], c0, 0, 0, 0);
        e1p = __builtin_amdgcn_mfma_f32_16x16x32_bf16(aF, bfrag[1], c1, 0, 0, 0);
    }

    #pragma unroll
    for (int it = 1; it < NIT; ++it) {
        // issue iter-it loads + MFMAs
        short8v aN = *(const short8v*)(lds + it * 512 + abase);
        f32x4 cna  = *(const f32x4*)(lds + 8192 + it * 64 + g * 16);
        f32x4 calN = *(const f32x4*)(lds + 9216 + it * 64 + g * 16);
        f32x4 c0, c1;
        #pragma unroll
        for (int q = 0; q < 4; ++q) { c0[q] = cna[q] + nb[0]; c1[q] = cna[q] + nb[1]; }
        f32x4 e0n = __builtin_amdgcn_mfma_f32_16x16x32_bf16(aN, bfrag[0], c0, 0, 0, 0);
        f32x4 e1n = __builtin_amdgcn_mfma_f32_16x16x32_bf16(aN, bfrag[1], c1, 0, 0, 0);

        // consume iter-(it-1) results while the MFMAs execute
        #pragma unroll
        for (int q = 0; q < 4; ++q) {
            float sq0 = fmaxf(e0p[q], 1e-12f);
            float dd0 = __builtin_amdgcn_sqrtf(sq0);
            float ex0 = __builtin_amdgcn_exp2f(EXPC * dd0);
            float pp0 = fmaf(SQRT5, dd0, fmaf(C53, sq0, 1.0f));
            acc0      = fmaf(pp0 * ex0, calp[q], acc0);
            float sq1 = fmaxf(e1p[q], 1e-12f);
            float dd1 = __builtin_amdgcn_sqrtf(sq1);
            float ex1 = __builtin_amdgcn_exp2f(EXPC * dd1);
            float pp1 = fmaf(SQRT5, dd1, fmaf(C53, sq1, 1.0f));
            acc1      = fmaf(pp1 * ex1, calp[q], acc1);
        }
        e0p = e0n; e1p = e1n; calp = calN;
    }
    // epilogue tail
    #pragma unroll
    for (int q = 0; q < 4; ++q) {
        float sq0 = fmaxf(e0p[q], 1e-12f);
        float dd0 = __builtin_amdgcn_sqrtf(sq0);
        float ex0 = __builtin_amdgcn_exp2f(EXPC * dd0);
        float pp0 = fmaf(SQRT5, dd0, fmaf(C53, sq0, 1.0f));
        acc0      = fmaf(pp0 * ex0, calp[q], acc0);
        float sq1 = fmaxf(e1p[q], 1e-12f);
        float dd1 = __builtin_amdgcn_sqrtf(sq1);
        float ex1 = __builtin_amdgcn_exp2f(EXPC * dd1);
        float pp1 = fmaf(SQRT5, dd1, fmaf(C53, sq1, 1.0f));
        acc1      = fmaf(pp1 * ex1, calp[q], acc1);
    }

    // reduce over the 4 row-groups; lanes 0-15 of each wave hold column sums
    acc0 += __shfl_xor(acc0, 16);
    acc0 += __shfl_xor(acc0, 32);
    acc1 += __shfl_xor(acc1, 16);
    acc1 += __shfl_xor(acc1, 32);
    if (g == 0) {
        float* dst = part + (size_t)blockIdx.y * M;
        if (j0 < M) dst[j0] = w * acc0;
        if (j1 < M) dst[j1] = w * acc1;
    }
}

__global__ __launch_bounds__(256) void reduce_cols(
    const float* __restrict__ part, float* __restrict__ out,
    int M, int nparts)
{
    const int j = blockIdx.x * 256 + threadIdx.x;
    if (j >= M) return;
    float a = 0.0f;
    for (int k = 0; k < nparts; ++k)
        a += part[(size_t)k * M + j];
    out[j] = a;
}

extern "C" void kernel_launch(void* const* d_in, const int* in_sizes, int n_in,
                              void* d_out, int out_size, void* d_ws, size_t ws_size,
                              hipStream_t stream) {
    const float* x     = (const float*)d_in[0];
    const float* xobs  = (const float*)d_in[1];
    const float* alpha = (const float*)d_in[2];
    const float* tfl   = (const float*)d_in[3];
    const float* ls    = (const float*)d_in[4];
    const int*   dro   = (const int*)d_in[5];
    const int*   drx   = (const int*)d_in[6];
    float* out = (float*)d_out;

    const int M  = in_sizes[0] / DPT;
    const int N  = in_sizes[1] / DPT;
    const int ND = in_sizes[5] / 2;
    const int nparts = (N + ROWS_PER_BLOCK - 1) / ROWS_PER_BLOCK;

    float* part = (float*)d_ws;   // nparts * M * 4 B

    dim3 grid((M + COLS_PER_BLOCK - 1) / COLS_PER_BLOCK, nparts);
    matern_main<<<grid, dim3(BLOCK), 0, stream>>>(
        x, xobs, alpha, tfl, ls, dro, drx, part, M, N, ND);

    reduce_cols<<<dim3((M + 255) / 256), dim3(256), 0, stream>>>(
        part, out, M, nparts);
}

// Round 7
// 26.987 us; speedup vs baseline: 2.0367x; 1.5905x over previous
//
#include <hip/hip_runtime.h>

// out[j] = sum_i alpha[i] * T[lab_obs[i], lab_x[j]] * matern52(xobs[i], x[j]; ls)
// N = M = 8192, D = 8, ND = 4; domain edges are multiples of 2048.
//
// u_ij = 5*log2e^2 * d_ij^2 computed ENTIRELY by one mfma_f32_16x16x32_bf16:
//   K slots  0-7 : ahi * bhi      (a pre-scaled by -2*5*log2e^2/ls^2)
//   K slots  8-15: alo * bhi
//   K slots 16-23: ahi * blo
//   K slot  24/25: na_hi/na_lo * 1  (na pre-scaled)
//   K slot  26/27: 1 * nb_hi/nb_lo  (nb pre-scaled)
//   C = 0 (hoisted zero quad). Then t=sqrt(u), k = (1+ln2*t+ln2^2/3*u)*exp2(-t).
// Tail = 5 VALU + 2 trans per pair. Transfer factor w is block-uniform and
// applied at the partial store; partials in d_ws, summed by reduce_cols.

typedef __attribute__((ext_vector_type(8))) short short8v;
typedef __attribute__((ext_vector_type(4))) float f32x4;
typedef __attribute__((ext_vector_type(4))) unsigned int u32x4;

#define BLOCK 256
#define DPT 8
#define COLS_PER_BLOCK 128
#define ROWS_PER_BLOCK 256
#define NIT (ROWS_PER_BLOCK / 16)
#define RSTRIDE 48               // bytes per packed LDS row: hi16 | lo16 | seed16

__device__ __forceinline__ void split_pair(float a0, float a1,
                                           unsigned& hi, unsigned& lo) {
    unsigned u0 = __builtin_bit_cast(unsigned, a0);
    unsigned u1 = __builtin_bit_cast(unsigned, a1);
    unsigned h0 = u0 & 0xffff0000u, h1 = u1 & 0xffff0000u;
    float r0 = a0 - __builtin_bit_cast(float, h0);
    float r1 = a1 - __builtin_bit_cast(float, h1);
    unsigned l0 = __builtin_bit_cast(unsigned, r0);
    unsigned l1 = __builtin_bit_cast(unsigned, r1);
    hi = (h0 >> 16) | h1;
    lo = (l0 >> 16) | (l1 & 0xffff0000u);
}

// split one nonnegative float into packed (hi | lo<<16) bf16 words
__device__ __forceinline__ unsigned split_scalar(float a) {
    unsigned u0 = __builtin_bit_cast(unsigned, a);
    unsigned h0 = u0 & 0xffff0000u;
    float r0 = a - __builtin_bit_cast(float, h0);
    unsigned l0 = __builtin_bit_cast(unsigned, r0);
    return (h0 >> 16) | (l0 & 0xffff0000u);
}

__global__ __launch_bounds__(256, 8) void matern_main(
    const float* __restrict__ x, const float* __restrict__ xobs,
    const float* __restrict__ alpha, const float* __restrict__ tfl,
    const float* __restrict__ ls, const int* __restrict__ dro,
    const int* __restrict__ drx,
    float* __restrict__ part, int M, int N, int ND)
{
    __shared__ __align__(16) char lds[ROWS_PER_BLOCK * RSTRIDE + ROWS_PER_BLOCK * 4];

    const int tid  = threadIdx.x;
    const int wave = tid >> 6;
    const int lane = tid & 63;
    const int g    = lane >> 4;
    const int r15  = lane & 15;

    const int colBase = blockIdx.x * COLS_PER_BLOCK;
    const int rowBase = blockIdx.y * ROWS_PER_BLOCK;

    // 5 * log2(e)^2 folded into the length-scale
    const float rls   = 1.0f / ls[0];
    const float rls2p = 10.406844905028039f * rls * rls;
    const float m2p   = -2.0f * rls2p;

    // ---- pack: thread t -> row rowBase+t into LDS (48B row + al) ----
    {
        const int i = rowBase + tid;
        unsigned hi[4] = {0,0,0,0}, lo[4] = {0,0,0,0};
        float na = 0.0f, al = 0.0f;
        if (i < N) {
            float4 p0 = *(const float4*)(xobs + (size_t)i * DPT);
            float4 p1 = *(const float4*)(xobs + (size_t)i * DPT + 4);
            float vv[8] = {p0.x, p0.y, p0.z, p0.w, p1.x, p1.y, p1.z, p1.w};
            #pragma unroll
            for (int k = 0; k < 4; ++k) {
                float a0 = vv[2*k], a1 = vv[2*k+1];
                na += a0*a0 + a1*a1;
                split_pair(a0*m2p, a1*m2p, hi[k], lo[k]);
            }
            na *= rls2p;
            al  = alpha[i];
        }
        char* rb = lds + tid * RSTRIDE;
        *(u32x4*)(rb)      = u32x4{hi[0], hi[1], hi[2], hi[3]};
        *(u32x4*)(rb + 16) = u32x4{lo[0], lo[1], lo[2], lo[3]};
        *(u32x4*)(rb + 32) = u32x4{split_scalar(na), 0x3F803F80u, 0u, 0u};
        *(float*)(lds + ROWS_PER_BLOCK * RSTRIDE + tid * 4) = al;
    }

    // ---- block-uniform transfer factor ----
    int labj = ND, labi = ND;
    for (int d = 0; d < ND; ++d) {
        if (colBase >= drx[2*d] && colBase < drx[2*d+1]) labj = d;
        if (rowBase >= dro[2*d] && rowBase < dro[2*d+1]) labi = d;
    }
    float w = 1.0f;
    if (labi != labj && labi < ND && labj < ND) {
        int a_ = min(labi, labj), b_ = max(labi, labj);
        int n  = a_ * (2*ND - a_ - 1) / 2 + (b_ - a_ - 1);
        w = 1.0f / (1.0f + __expf(-tfl[n]));
    }

    // ---- column fragments: 2 groups of 16 cols per wave, in registers ----
    const int j0 = colBase + wave * 32 + r15;
    const int j1 = j0 + 16;
    short8v bfrag[2];
    #pragma unroll
    for (int c = 0; c < 2; ++c) {
        const int j = (c == 0) ? j0 : j1;
        float vv[8];
        if (j < M) {
            float4 p0 = *(const float4*)(x + (size_t)j * DPT);
            float4 p1 = *(const float4*)(x + (size_t)j * DPT + 4);
            vv[0]=p0.x; vv[1]=p0.y; vv[2]=p0.z; vv[3]=p0.w;
            vv[4]=p1.x; vv[5]=p1.y; vv[6]=p1.z; vv[7]=p1.w;
        } else {
            #pragma unroll
            for (int k = 0; k < 8; ++k) vv[k] = 0.0f;
        }
        float s2 = 0.0f;
        unsigned bh[4], bl[4];
        #pragma unroll
        for (int k = 0; k < 4; ++k) {
            s2 += vv[2*k]*vv[2*k] + vv[2*k+1]*vv[2*k+1];
            split_pair(vv[2*k], vv[2*k+1], bh[k], bl[k]);
        }
        const unsigned nbw = split_scalar(s2 * rls2p);
        u32x4 bw;
        #pragma unroll
        for (int k = 0; k < 4; ++k) {
            unsigned seed = (k == 0) ? 0x3F803F80u : ((k == 1) ? nbw : 0u);
            bw[k] = (g == 3) ? seed : ((g == 2) ? bl[k] : bh[k]);
        }
        bfrag[c] = __builtin_bit_cast(short8v, bw);
    }

    __syncthreads();

    // ---- compute: NIT iterations of 16 rows x 32 cols ----
    const float LN2   = 0.6931471805599453f;
    const float LN2S3 = 0.16015660576973906f;   // ln2^2 / 3

    // A-fragment part select: g0/g2 -> hi, g1 -> lo, g3 -> seed
    const int poff  = (g == 1) ? 16 : ((g == 3) ? 32 : 0);
    const char* pa  = lds + r15 * RSTRIDE + poff;
    const char* pal = lds + ROWS_PER_BLOCK * RSTRIDE + g * 16;

    f32x4 zq = {0.0f, 0.0f, 0.0f, 0.0f};
    float acc0 = 0.0f, acc1 = 0.0f;

    #pragma unroll 4
    for (int it = 0; it < NIT; ++it) {
        short8v afrag = *(const short8v*)(pa + it * (16 * RSTRIDE));
        f32x4   cal   = *(const f32x4*)(pal + it * 64);

        f32x4 d0 = __builtin_amdgcn_mfma_f32_16x16x32_bf16(afrag, bfrag[0], zq, 0, 0, 0);
        f32x4 d1 = __builtin_amdgcn_mfma_f32_16x16x32_bf16(afrag, bfrag[1], zq, 0, 0, 0);

        #pragma unroll
        for (int q = 0; q < 4; ++q) {
            float u0 = fmaxf(d0[q], 1e-20f);
            float t0 = __builtin_amdgcn_sqrtf(u0);
            float e0 = __builtin_amdgcn_exp2f(-t0);
            float p0 = fmaf(LN2, t0, fmaf(LN2S3, u0, 1.0f));
            acc0     = fmaf(p0 * e0, cal[q], acc0);
            float u1 = fmaxf(d1[q], 1e-20f);
            float t1 = __builtin_amdgcn_sqrtf(u1);
            float e1 = __builtin_amdgcn_exp2f(-t1);
            float p1 = fmaf(LN2, t1, fmaf(LN2S3, u1, 1.0f));
            acc1     = fmaf(p1 * e1, cal[q], acc1);
        }
    }

    // reduce over the 4 row-groups; lanes 0-15 of each wave hold column sums
    acc0 += __shfl_xor(acc0, 16);
    acc0 += __shfl_xor(acc0, 32);
    acc1 += __shfl_xor(acc1, 16);
    acc1 += __shfl_xor(acc1, 32);
    if (g == 0) {
        float* dst = part + (size_t)blockIdx.y * M;
        if (j0 < M) dst[j0] = w * acc0;
        if (j1 < M) dst[j1] = w * acc1;
    }
}

__global__ __launch_bounds__(128) void reduce_cols(
    const float* __restrict__ part, float* __restrict__ out,
    int M, int nparts)
{
    const int j = blockIdx.x * 128 + threadIdx.x;
    if (j >= M) return;
    float a = 0.0f;
    #pragma unroll 8
    for (int k = 0; k < nparts; ++k)
        a += part[(size_t)k * M + j];
    out[j] = a;
}

extern "C" void kernel_launch(void* const* d_in, const int* in_sizes, int n_in,
                              void* d_out, int out_size, void* d_ws, size_t ws_size,
                              hipStream_t stream) {
    const float* x     = (const float*)d_in[0];
    const float* xobs  = (const float*)d_in[1];
    const float* alpha = (const float*)d_in[2];
    const float* tfl   = (const float*)d_in[3];
    const float* ls    = (const float*)d_in[4];
    const int*   dro   = (const int*)d_in[5];
    const int*   drx   = (const int*)d_in[6];
    float* out = (float*)d_out;

    const int M  = in_sizes[0] / DPT;
    const int N  = in_sizes[1] / DPT;
    const int ND = in_sizes[5] / 2;
    const int nparts = (N + ROWS_PER_BLOCK - 1) / ROWS_PER_BLOCK;

    float* part = (float*)d_ws;   // nparts * M * 4 B

    dim3 grid((M + COLS_PER_BLOCK - 1) / COLS_PER_BLOCK, nparts);
    matern_main<<<grid, dim3(BLOCK), 0, stream>>>(
        x, xobs, alpha, tfl, ls, dro, drx, part, M, N, ND);

    reduce_cols<<<dim3((M + 127) / 128), dim3(128), 0, stream>>>(
        part, out, M, nparts);
}